// Round 1
// baseline (386.853 us; speedup 1.0000x reference)
//
#include <hip/hip_runtime.h>
#include <hip/hip_bf16.h>
#include <stdint.h>

// Problem dims (fixed by setup_inputs)
#define M_TOTAL 2048     // B (feats rows)
#define N_TOTAL 16384    // Bs*TOPK (support rows)
#define K_TOTAL 2048     // C
#define NPARTS  256      // 128 n-tiles * 2 n-waves

typedef __attribute__((ext_vector_type(8))) short short8;   // 8 x bf16 (4 VGPRs)
typedef __attribute__((ext_vector_type(4))) float floatx4;  // MFMA C/D frag

// ---------------------------------------------------------------- conversion
__device__ __forceinline__ uint32_t pack_bf16_2(float lo, float hi) {
    uint32_t ul = __float_as_uint(lo);
    uint32_t uh = __float_as_uint(hi);
    ul = (ul + 0x7fffu + ((ul >> 16) & 1u)) >> 16;   // RNE
    uh = (uh + 0x7fffu + ((uh >> 16) & 1u)) >> 16;
    return ul | (uh << 16);
}

__global__ void cvt_bf16(const float* __restrict__ a, const float* __restrict__ b,
                         uint2* __restrict__ oa, uint2* __restrict__ ob) {
    const long t1 = (long)M_TOTAL * K_TOTAL / 4;       // float4 count of feats
    const long tt = t1 + (long)N_TOTAL * K_TOTAL / 4;  // total float4s
    for (long i = (long)blockIdx.x * blockDim.x + threadIdx.x; i < tt;
         i += (long)gridDim.x * blockDim.x) {
        const float4* src; uint2* dst; long j;
        if (i < t1) { src = (const float4*)a; dst = oa; j = i; }
        else        { src = (const float4*)b; dst = ob; j = i - t1; }
        float4 v = src[j];
        uint2 o;
        o.x = pack_bf16_2(v.x, v.y);
        o.y = pack_bf16_2(v.z, v.w);
        dst[j] = o;
    }
}

// ---------------------------------------------------------------- GEMM + fused epilogue
__device__ __forceinline__ void load16(const void* g, void* l) {
    __builtin_amdgcn_global_load_lds(
        (const __attribute__((address_space(1))) void*)g,
        (__attribute__((address_space(3))) void*)l, 16, 0, 0);
}

__global__ __launch_bounds__(256) void gemm_lp(
        const short* __restrict__ Abf, const short* __restrict__ Bbf,
        const int* __restrict__ labels, const int* __restrict__ labels_s,
        float* __restrict__ pminp, float* __restrict__ psump) {
    __shared__ __align__(16) short lsA[128 * 32];
    __shared__ __align__(16) short lsB[128 * 32];
    __shared__ int lab_m[128];
    __shared__ int lab_n[128];

    const int t    = threadIdx.x;
    const int lane = t & 63;
    const int wave = t >> 6;
    const int wm   = wave >> 1;   // row half (0..1)
    const int wn   = wave & 1;    // col half (0..1)
    const int m0   = blockIdx.y * 128;
    const int n0   = blockIdx.x * 128;

    if (t < 128) lab_m[t] = labels[m0 + t];
    else         lab_n[t - 128] = labels_s[n0 + t - 128];

    // global->LDS staging: thread t loads 16B chunk q=t (round0) and q=256+t (round1)
    // chunk q -> tile row q>>2, k-chunk q&3 (8 bf16 each). LDS layout row-major [128][32].
    const int  rq = t >> 2;
    const int  kc = t & 3;
    const long aOff0 = (long)(m0 + rq) * K_TOTAL + kc * 8;
    const long aOff1 = (long)(m0 + 64 + rq) * K_TOTAL + kc * 8;
    const long bOff0 = (long)(n0 + rq) * K_TOTAL + kc * 8;
    const long bOff1 = (long)(n0 + 64 + rq) * K_TOTAL + kc * 8;
    short* lA0 = lsA + wave * 512;           // wave-uniform LDS base; HW adds lane*16B
    short* lA1 = lsA + 2048 + wave * 512;
    short* lB0 = lsB + wave * 512;
    short* lB1 = lsB + 2048 + wave * 512;

    // MFMA fragment LDS pointers (constant across K iterations)
    const int quad = lane >> 4;
    const int lcol = lane & 15;
    const int koff = quad * 8;               // A[m=lcol][k=quad*8+j]
    const short* pa[4]; const short* pb[4];
#pragma unroll
    for (int i = 0; i < 4; ++i) {
        pa[i] = lsA + (wm * 64 + i * 16 + lcol) * 32 + koff;
        pb[i] = lsB + (wn * 64 + i * 16 + lcol) * 32 + koff;
    }

    floatx4 acc[4][4];
#pragma unroll
    for (int mi = 0; mi < 4; ++mi)
#pragma unroll
        for (int ni = 0; ni < 4; ++ni)
            acc[mi][ni] = (floatx4){0.f, 0.f, 0.f, 0.f};

    for (int kt = 0; kt < K_TOTAL / 32; ++kt) {
        const long ko = (long)kt * 32;
        __syncthreads();                         // previous iter's compute done
        load16(Abf + aOff0 + ko, lA0);
        load16(Abf + aOff1 + ko, lA1);
        load16(Bbf + bOff0 + ko, lB0);
        load16(Bbf + bOff1 + ko, lB1);
        __syncthreads();                         // drains vmcnt -> tiles ready
        short8 av[4], bv[4];
#pragma unroll
        for (int i = 0; i < 4; ++i) av[i] = *(const short8*)pa[i];
#pragma unroll
        for (int i = 0; i < 4; ++i) bv[i] = *(const short8*)pb[i];
#pragma unroll
        for (int mi = 0; mi < 4; ++mi)
#pragma unroll
            for (int ni = 0; ni < 4; ++ni)
                acc[mi][ni] = __builtin_amdgcn_mfma_f32_16x16x32_bf16(
                    av[mi], bv[ni], acc[mi][ni], 0, 0, 0);
    }

    // Epilogue: e = exp(sim/TEMP) = exp2(sim * 1/(0.05*ln2)); masked min/sum over cols.
    // C/D layout: col = lane&15, row = quad*4 + reg  (m89/m91 verified)
    const float scale = 28.853900817779268f;     // 20 * log2(e)
#pragma unroll
    for (int mi = 0; mi < 4; ++mi) {
#pragma unroll
        for (int r = 0; r < 4; ++r) {
            const int row_local = wm * 64 + mi * 16 + quad * 4 + r;
            const int lab = lab_m[row_local];
            float minv = __builtin_inff();
            float sumv = 0.f;
#pragma unroll
            for (int ni = 0; ni < 4; ++ni) {
                const int col_local = wn * 64 + ni * 16 + lcol;
                const float e = exp2f(acc[mi][ni][r] * scale);
                const bool pos = (lab_n[col_local] == lab);
                minv = pos ? fminf(minv, e) : minv;
                sumv = pos ? sumv : (sumv + e);
            }
#pragma unroll
            for (int off = 1; off < 16; off <<= 1) {
                minv = fminf(minv, __shfl_xor(minv, off, 16));
                sumv += __shfl_xor(sumv, off, 16);
            }
            if (lcol == 0) {
                const long idx = (long)(blockIdx.x * 2 + wn) * M_TOTAL + m0 + row_local;
                pminp[idx] = minv;
                psump[idx] = sumv;
            }
        }
    }
}

// ---------------------------------------------------------------- row fold + mean
__global__ void reduce_rows(const float* __restrict__ pminp,
                            const float* __restrict__ psump,
                            float* __restrict__ loss) {
    const int b = blockIdx.x * 256 + threadIdx.x;   // 8 blocks x 256 = 2048 rows
    float m = __builtin_inff();
    float s = 0.f;
    for (int j = 0; j < NPARTS; ++j) {
        m = fminf(m, pminp[(long)j * M_TOTAL + b]);
        s += psump[(long)j * M_TOTAL + b];
    }
    loss[b] = -logf(m / (m + s + 1e-6f) + 1e-6f);
}

__global__ void final_mean(const float* __restrict__ loss, float* __restrict__ out) {
    float s = 0.f;
    for (int i = threadIdx.x; i < M_TOTAL; i += 256) s += loss[i];
#pragma unroll
    for (int off = 32; off > 0; off >>= 1) s += __shfl_xor(s, off, 64);
    __shared__ float wsum[4];
    if ((threadIdx.x & 63) == 0) wsum[threadIdx.x >> 6] = s;
    __syncthreads();
    if (threadIdx.x == 0)
        out[0] = (wsum[0] + wsum[1] + wsum[2] + wsum[3]) * (1.0f / (float)M_TOTAL);
}

// ---------------------------------------------------------------- launcher
extern "C" void kernel_launch(void* const* d_in, const int* in_sizes, int n_in,
                              void* d_out, int out_size, void* d_ws, size_t ws_size,
                              hipStream_t stream) {
    const float* feats    = (const float*)d_in[0];
    const float* feats_s  = (const float*)d_in[1];
    const int*   labels   = (const int*)d_in[2];
    const int*   labels_s = (const int*)d_in[3];
    float*       out      = (float*)d_out;

    char* ws = (char*)d_ws;
    short* Abf   = (short*)(ws);                          //  8,388,608 B
    short* Bbf   = (short*)(ws + 8388608);                // 67,108,864 B
    float* pminp = (float*)(ws + 75497472);               //  2,097,152 B
    float* psump = (float*)(ws + 77594624);               //  2,097,152 B
    float* loss  = (float*)(ws + 79691776);               //      8,192 B

    cvt_bf16<<<2048, 256, 0, stream>>>(feats, feats_s, (uint2*)Abf, (uint2*)Bbf);

    dim3 grid(N_TOTAL / 128, M_TOTAL / 128);              // 128 x 16
    gemm_lp<<<grid, 256, 0, stream>>>(Abf, Bbf, labels, labels_s, pminp, psump);

    reduce_rows<<<8, 256, 0, stream>>>(pminp, psump, loss);
    final_mean<<<1, 256, 0, stream>>>(loss, out);
}

// Round 2
// 378.112 us; speedup vs baseline: 1.0231x; 1.0231x over previous
//
#include <hip/hip_runtime.h>
#include <hip/hip_bf16.h>
#include <stdint.h>

// Problem dims (fixed by setup_inputs)
#define M_TOTAL 2048     // B (feats rows)
#define N_TOTAL 16384    // Bs*TOPK (support rows)
#define K_TOTAL 2048     // C
#define NPARTS  256      // 128 n-tiles * 2 n-waves

typedef __attribute__((ext_vector_type(8))) short short8;   // 8 x bf16 (4 VGPRs)
typedef __attribute__((ext_vector_type(4))) float floatx4;  // MFMA C/D frag

// ---------------------------------------------------------------- conversion
__device__ __forceinline__ uint32_t pack_bf16_2(float lo, float hi) {
    uint32_t ul = __float_as_uint(lo);
    uint32_t uh = __float_as_uint(hi);
    ul = (ul + 0x7fffu + ((ul >> 16) & 1u)) >> 16;   // RNE
    uh = (uh + 0x7fffu + ((uh >> 16) & 1u)) >> 16;
    return ul | (uh << 16);
}

__global__ void cvt_bf16(const float4* __restrict__ src, uint2* __restrict__ dst, int n4) {
    int i = blockIdx.x * blockDim.x + threadIdx.x;
    const int stride = gridDim.x * blockDim.x;
    for (; i < n4; i += stride) {
        float4 v = src[i];
        uint2 o;
        o.x = pack_bf16_2(v.x, v.y);
        o.y = pack_bf16_2(v.z, v.w);
        dst[i] = o;
    }
}

// ---------------------------------------------------------------- GEMM + fused epilogue
__device__ __forceinline__ void load16(const void* g, void* l) {
    __builtin_amdgcn_global_load_lds(
        (const __attribute__((address_space(1))) void*)g,
        (__attribute__((address_space(3))) void*)l, 16, 0, 0);
}

// LDS tile layout: 128 rows x 4 k-chunks (16B each). Physical chunk position
// within a row is XOR-swizzled: p = (q + (row>>1)) & 3, so the ds_read_b128
// fragment loads (row stride 64B within a quarter-wave) spread across all 8
// bank-chunk slots -> conflict-free. The swizzle is applied on the GLOBAL
// address side of global_load_lds (LDS dest must remain base + lane*16B).
__global__ __launch_bounds__(256) void gemm_lp(
        const short* __restrict__ Abf, const short* __restrict__ Bbf,
        const int* __restrict__ labels, const int* __restrict__ labels_s,
        float* __restrict__ pminp, float* __restrict__ psump) {
    __shared__ __align__(16) short lsA[128 * 32];
    __shared__ __align__(16) short lsB[128 * 32];
    __shared__ int lab_m[128];
    __shared__ int lab_n[128];

    const int t    = threadIdx.x;
    const int lane = t & 63;
    const int wave = t >> 6;
    const int wm   = wave >> 1;   // row half (0..1)
    const int wn   = wave & 1;    // col half (0..1)
    const int m0   = blockIdx.y * 128;
    const int n0   = blockIdx.x * 128;

    if (t < 128) lab_m[t] = labels[m0 + t];
    else         lab_n[t - 128] = labels_s[n0 + t - 128];

    // staging: thread t fills physical chunk t (round0) / 256+t (round1).
    // physical row = t>>2, physical pos p = t&3  ->  global k-chunk
    // q = (p - (row>>1)) & 3 = ((t&3) - (t>>3)) & 3   (same for both rounds)
    const int  rq = t >> 2;
    const int  kq = ((t & 3) - (t >> 3)) & 3;
    const long aOff0 = (long)(m0 + rq) * K_TOTAL + kq * 8;
    const long aOff1 = (long)(m0 + 64 + rq) * K_TOTAL + kq * 8;
    const long bOff0 = (long)(n0 + rq) * K_TOTAL + kq * 8;
    const long bOff1 = (long)(n0 + 64 + rq) * K_TOTAL + kq * 8;
    short* lA0 = lsA + wave * 512;           // wave-uniform LDS base; HW adds lane*16B
    short* lA1 = lsA + 2048 + wave * 512;
    short* lB0 = lsB + wave * 512;
    short* lB1 = lsB + 2048 + wave * 512;

    // MFMA fragment LDS pointers: global chunk quad of row R lives at
    // physical pos (quad + (R>>1)) & 3
    const int quad = lane >> 4;
    const int lcol = lane & 15;
    const short* pa[4]; const short* pb[4];
#pragma unroll
    for (int i = 0; i < 4; ++i) {
        const int Ra = wm * 64 + i * 16 + lcol;
        const int Rb = wn * 64 + i * 16 + lcol;
        pa[i] = lsA + Ra * 32 + (((quad + (Ra >> 1)) & 3) * 8);
        pb[i] = lsB + Rb * 32 + (((quad + (Rb >> 1)) & 3) * 8);
    }

    floatx4 acc[4][4];
#pragma unroll
    for (int mi = 0; mi < 4; ++mi)
#pragma unroll
        for (int ni = 0; ni < 4; ++ni)
            acc[mi][ni] = (floatx4){0.f, 0.f, 0.f, 0.f};

    for (int kt = 0; kt < K_TOTAL / 32; ++kt) {
        const long ko = (long)kt * 32;
        __syncthreads();                         // previous iter's compute done
        load16(Abf + aOff0 + ko, lA0);
        load16(Abf + aOff1 + ko, lA1);
        load16(Bbf + bOff0 + ko, lB0);
        load16(Bbf + bOff1 + ko, lB1);
        __syncthreads();                         // drains vmcnt -> tiles ready
        short8 av[4], bv[4];
#pragma unroll
        for (int i = 0; i < 4; ++i) av[i] = *(const short8*)pa[i];
#pragma unroll
        for (int i = 0; i < 4; ++i) bv[i] = *(const short8*)pb[i];
#pragma unroll
        for (int mi = 0; mi < 4; ++mi)
#pragma unroll
            for (int ni = 0; ni < 4; ++ni)
                acc[mi][ni] = __builtin_amdgcn_mfma_f32_16x16x32_bf16(
                    av[mi], bv[ni], acc[mi][ni], 0, 0, 0);
    }

    // Epilogue: e = exp(sim/TEMP) = exp2(sim * 28.8539); masked min/sum over cols.
    // C/D layout: col = lane&15, row = quad*4 + reg  (m89/m91 verified)
    const float scale = 28.853900817779268f;     // 20 * log2(e)
#pragma unroll
    for (int mi = 0; mi < 4; ++mi) {
#pragma unroll
        for (int r = 0; r < 4; ++r) {
            const int row_local = wm * 64 + mi * 16 + quad * 4 + r;
            const int lab = lab_m[row_local];
            float minv = __builtin_inff();
            float sumv = 0.f;
#pragma unroll
            for (int ni = 0; ni < 4; ++ni) {
                const int col_local = wn * 64 + ni * 16 + lcol;
                const float e = exp2f(acc[mi][ni][r] * scale);
                const bool pos = (lab_n[col_local] == lab);
                minv = pos ? fminf(minv, e) : minv;
                sumv = pos ? sumv : (sumv + e);
            }
#pragma unroll
            for (int off = 1; off < 16; off <<= 1) {
                minv = fminf(minv, __shfl_xor(minv, off, 16));
                sumv += __shfl_xor(sumv, off, 16);
            }
            if (lcol == 0) {
                // partials laid out [row][part] so reduce_rows reads coalesced
                const long idx = (long)(m0 + row_local) * NPARTS + blockIdx.x * 2 + wn;
                pminp[idx] = minv;
                psump[idx] = sumv;
            }
        }
    }
}

// ---------------------------------------------------------------- row fold + mean
// one wave per row, 512 blocks x 4 waves = 2048 waves
__global__ __launch_bounds__(256) void reduce_rows(
        const float* __restrict__ pminp, const float* __restrict__ psump,
        float* __restrict__ loss) {
    const int row  = blockIdx.x * 4 + (threadIdx.x >> 6);
    const int lane = threadIdx.x & 63;
    float m = __builtin_inff();
    float s = 0.f;
#pragma unroll
    for (int k = 0; k < NPARTS / 64; ++k) {
        const long j = (long)row * NPARTS + lane + k * 64;
        m = fminf(m, pminp[j]);
        s += psump[j];
    }
#pragma unroll
    for (int off = 1; off < 64; off <<= 1) {
        m = fminf(m, __shfl_xor(m, off, 64));
        s += __shfl_xor(s, off, 64);
    }
    if (lane == 0) loss[row] = -logf(m / (m + s + 1e-6f) + 1e-6f);
}

__global__ void final_mean(const float* __restrict__ loss, float* __restrict__ out) {
    float s = 0.f;
    for (int i = threadIdx.x; i < M_TOTAL; i += 256) s += loss[i];
#pragma unroll
    for (int off = 32; off > 0; off >>= 1) s += __shfl_xor(s, off, 64);
    __shared__ float wsum[4];
    if ((threadIdx.x & 63) == 0) wsum[threadIdx.x >> 6] = s;
    __syncthreads();
    if (threadIdx.x == 0)
        out[0] = (wsum[0] + wsum[1] + wsum[2] + wsum[3]) * (1.0f / (float)M_TOTAL);
}

// ---------------------------------------------------------------- launcher
extern "C" void kernel_launch(void* const* d_in, const int* in_sizes, int n_in,
                              void* d_out, int out_size, void* d_ws, size_t ws_size,
                              hipStream_t stream) {
    const float* feats    = (const float*)d_in[0];
    const float* feats_s  = (const float*)d_in[1];
    const int*   labels   = (const int*)d_in[2];
    const int*   labels_s = (const int*)d_in[3];
    float*       out      = (float*)d_out;

    char* ws = (char*)d_ws;
    short* Abf   = (short*)(ws);                          //  8,388,608 B
    short* Bbf   = (short*)(ws + 8388608);                // 67,108,864 B
    float* pminp = (float*)(ws + 75497472);               //  2,097,152 B
    float* psump = (float*)(ws + 77594624);               //  2,097,152 B
    float* loss  = (float*)(ws + 79691776);               //      8,192 B

    cvt_bf16<<<512,  256, 0, stream>>>((const float4*)feats,   (uint2*)Abf,
                                       M_TOTAL * K_TOTAL / 4);
    cvt_bf16<<<2048, 256, 0, stream>>>((const float4*)feats_s, (uint2*)Bbf,
                                       N_TOTAL * K_TOTAL / 4);

    dim3 grid(N_TOTAL / 128, M_TOTAL / 128);              // 128 x 16
    gemm_lp<<<grid, 256, 0, stream>>>(Abf, Bbf, labels, labels_s, pminp, psump);

    reduce_rows<<<512, 256, 0, stream>>>(pminp, psump, loss);
    final_mean<<<1, 256, 0, stream>>>(loss, out);
}